// Round 5
// baseline (6674.612 us; speedup 1.0000x reference)
//
#include <hip/hip_runtime.h>

#define TSTEPS 512
#define BATCH  256
#define HID    256
#define OUTC   256
#define L2E 1.442695040888963f

typedef _Float16 half8 __attribute__((ext_vector_type(8)));
typedef float    f32x4 __attribute__((ext_vector_type(4)));
union G16 { unsigned long long u2[2]; unsigned u[4]; half8 h; };

#if __has_builtin(__builtin_amdgcn_exp2f)
#define EXP2F __builtin_amdgcn_exp2f
#else
#define EXP2F exp2f
#endif
#if __has_builtin(__builtin_amdgcn_rcpf)
#define RCPF __builtin_amdgcn_rcpf
#else
#define RCPF(x) (1.0f/(x))
#endif

// rings in d_out scratch
#define H0_SLOTS 16
#define PA_SLOTS 8
#define H0RING_QW (H0_SLOTS*16*16*128)   // 524288  (4 MB)
#define PARING_QW (PA_SLOTS*16*8*1024)   // 1048576 (8 MB)

__device__ __forceinline__ void st64(unsigned long long* p, unsigned long long v){
  __hip_atomic_store(p, v, __ATOMIC_RELAXED, __HIP_MEMORY_SCOPE_AGENT);
}
__device__ __forceinline__ unsigned long long ld64(const unsigned long long* p){
  return __hip_atomic_load(p, __ATOMIC_RELAXED, __HIP_MEMORY_SCOPE_AGENT);
}
__device__ __forceinline__ void st32(unsigned* p, unsigned v){
  __hip_atomic_store(p, v, __ATOMIC_RELAXED, __HIP_MEMORY_SCOPE_AGENT);
}
__device__ __forceinline__ unsigned ld32(const unsigned* p){
  return __hip_atomic_load(p, __ATOMIC_RELAXED, __HIP_MEMORY_SCOPE_AGENT);
}
__device__ __forceinline__ unsigned pack2(float a, float b){
  _Float16 x=(_Float16)a, y=(_Float16)b;
  return (unsigned)__builtin_bit_cast(unsigned short,x)
       | ((unsigned)__builtin_bit_cast(unsigned short,y)<<16);
}
__device__ __forceinline__ float f16lo(unsigned d){
  return (float)__builtin_bit_cast(_Float16,(unsigned short)(d & 0xffffu));
}
__device__ __forceinline__ float f16hi(unsigned d){
  return (float)__builtin_bit_cast(_Float16,(unsigned short)(d >> 16));
}
__device__ __forceinline__ float sigx(float x){
  return RCPF(1.f + EXP2F(-L2E * x));
}
__device__ __forceinline__ float tanhx(float x){
  return 1.f - 2.f*RCPF(1.f + EXP2F((2.f*L2E) * x));
}
// acc/weight slot i (0..7) -> gate-column index:  i<5: (g=i>>1, jt=i&1);
// 5:(2,1) 6:(3,0) 7:(3,1).  Slots 0-4 = VGPR, 5-6 = LDS, 7 = L2-stream.
__device__ __forceinline__ int ngof(int i, int nb){
  int g  = (i<5) ? (i>>1) : (i==5 ? 2 : 3);
  int jt = (i<5) ? (i&1)  : (i==5 ? 1 : (i==6 ? 0 : 1));
  return g*256 + nb + jt*16;
}

// ---------------- prep kernels ----------------
__global__ void prep_convert(const float* __restrict__ Wih, const float* __restrict__ Whh,
                             const float* __restrict__ fcw, const float* __restrict__ bih,
                             const float* __restrict__ bhh,
                             _Float16* __restrict__ wh0, _Float16* __restrict__ wi1,
                             _Float16* __restrict__ wh1, _Float16* __restrict__ fcwh,
                             float* __restrict__ bias1)
{
  int i = blockIdx.x*256 + threadIdx.x;
  wh0[i] = (_Float16)Whh[i];
  wi1[i] = (_Float16)Wih[262144 + i];
  wh1[i] = (_Float16)Whh[262144 + i];
  if (i < 65536) fcwh[i] = (_Float16)fcw[i];
  if (i < 1024)  bias1[i] = bih[1024+i] + bhh[1024+i];
}

// gxT[grp][n][row16] = x[b]*Wih0[n] + bih0[n] + bhh0[n], b = grp*16+row16
__global__ void prep_gx0(const float* __restrict__ x, const float* __restrict__ Wih,
                         const float* __restrict__ bih, const float* __restrict__ bhh,
                         float* __restrict__ gxT)
{
  int gid = blockIdx.x*256 + threadIdx.x;
  int b = gid >> 10, n = gid & 1023;
  const float4* xv = (const float4*)(x + (size_t)b*256);
  const float4* wv = (const float4*)(Wih + (size_t)n*256);
  float s = bih[n] + bhh[n];
  #pragma unroll 8
  for (int k=0;k<64;k++){
    float4 a = xv[k], c = wv[k];
    s += a.x*c.x + a.y*c.y + a.z*c.z + a.w*c.w;
  }
  gxT[((size_t)(b>>4)*1024 + n)*16 + (b&15)] = s;
}

__global__ void zero_scratch(unsigned long long* __restrict__ base, int total){
  int i = blockIdx.x*256 + threadIdx.x;
  if (i < total) st64(base + i, 0ull);
}

// one K=256 GEMM micro-step: acc[0..7] += shc(16x256) x W(Nt slots)
__device__ __forceinline__ void mfma_step(const _Float16* shc, const _Float16* WL,
    const half8 wreg[5][8], const half8 wstr[8], int c16, int kg, int w, f32x4 acc[8])
{
  const int swz = c16 & 7;
  half8 af[8];
  #pragma unroll
  for (int kt=0;kt<8;kt++)
    af[kt] = *(const half8*)&shc[c16*256 + ((kt*4+kg)^swz)*8];
  const _Float16* wl5 = WL + (size_t)(w*32      + c16)*256;
  const _Float16* wl6 = WL + (size_t)(w*32 + 16 + c16)*256;
  #pragma unroll
  for (int kt=0;kt<8;kt++){
    int gq = ((kt*4+kg)^swz)*8;
    acc[0] = __builtin_amdgcn_mfma_f32_16x16x32_f16(af[kt], wreg[0][kt], acc[0],0,0,0);
    acc[1] = __builtin_amdgcn_mfma_f32_16x16x32_f16(af[kt], wreg[1][kt], acc[1],0,0,0);
    acc[2] = __builtin_amdgcn_mfma_f32_16x16x32_f16(af[kt], wreg[2][kt], acc[2],0,0,0);
    acc[3] = __builtin_amdgcn_mfma_f32_16x16x32_f16(af[kt], wreg[3][kt], acc[3],0,0,0);
    acc[4] = __builtin_amdgcn_mfma_f32_16x16x32_f16(af[kt], wreg[4][kt], acc[4],0,0,0);
    acc[5] = __builtin_amdgcn_mfma_f32_16x16x32_f16(af[kt], *(const half8*)&wl5[gq], acc[5],0,0,0);
    acc[6] = __builtin_amdgcn_mfma_f32_16x16x32_f16(af[kt], *(const half8*)&wl6[gq], acc[6],0,0,0);
    acc[7] = __builtin_amdgcn_mfma_f32_16x16x32_f16(af[kt], wstr[kt], acc[7],0,0,0);
  }
}

// ================= 3-role fused LSTM: 48 WGs =================
// role0 (blk 0-15):  layer-0 recurrence, self-contained per group (16 rows).
// role1 (blk 16-31): partA = Wi1*h0(t)+bias, streams h0ring -> paring.
// role2 (blk 32-47): layer-1 recurrence, h1 in LDS, consumes paring, seq1 out.
// NOTE: weight/gx pointers intentionally NOT __restrict__ — per-step reloads
// must not be LICM-hoisted into permanently-live registers.
__global__ __launch_bounds__(512,2) void lstm3(
    const float* gxT, const _Float16* Wh0, const _Float16* Wi1, const _Float16* Wh1,
    const float* bias1, const float* h_in, const float* c_in,
    unsigned* seq1dw, unsigned long long* h0r, unsigned long long* par,
    unsigned* flagC, unsigned* flagB)
{
  __shared__ __align__(16) _Float16 WL[65536];   // 128 KB: LDS weight slots 5,6
  __shared__ __align__(16) _Float16 shH[8192];   // 16 KB: h tile, double-buffered

  const int blk = blockIdx.x;
  const int role = blk >> 4;
  const int grp = blk & 15;
  const int b0 = grp*16;
  const int tid = threadIdx.x;
  const int w = tid>>6, l = tid&63, c16 = l&15, kg = l>>4;
  const int nb = w*32 + c16;

  const _Float16* Wg = (role==0) ? Wh0 : (role==1) ? Wi1 : Wh1;

  // ---- weights: LDS slots (2 Nt per wave) ----
  for (int idx = tid; idx < 8192; idx += 512){
    int row = idx >> 5, q = idx & 31;
    int w_ = row >> 5, i16 = (row>>4)&1, c_ = row & 15;
    int ng = i16 ? (3*256 + w_*32 + c_) : (2*256 + w_*32 + 16 + c_);
    half8 v = *(const half8*)(Wg + (size_t)ng*256 + q*8);
    *(half8*)&WL[row*256 + (q ^ (c_&7))*8] = v;
  }
  // ---- weights: VGPR slots 0..4 ----
  half8 wreg[5][8];
  #pragma unroll
  for (int i=0;i<5;i++){
    int ng = ngof(i, nb);
    #pragma unroll
    for (int kt=0;kt<8;kt++)
      wreg[i][kt] = *(const half8*)(Wg + (size_t)ng*256 + kt*32 + kg*8);
  }
  // ---- weights: streamed slot 7 ----
  const _Float16* wstrp = Wg + (size_t)(3*256 + nb + 16)*256 + kg*8;
  half8 wstr[8];
  #pragma unroll
  for (int kt=0;kt<8;kt++) wstr[kt] = *(const half8*)(wstrp + kt*32);

  if (role == 0){
    // ================= layer-0 recurrence =================
    { int row = tid>>5, q = tid&31;
      const float* s = h_in + (size_t)(b0+row)*256 + q*8;
      half8 v;
      #pragma unroll
      for (int qq=0;qq<8;qq++) v[qq] = (_Float16)s[qq];
      *(half8*)&shH[row*256 + (q^(row&7))*8] = v; }            // buf 0 = h(-1)
    float cs[8];
    #pragma unroll
    for (int jtl=0;jtl<2;jtl++)
      #pragma unroll
      for (int r=0;r<4;r++)
        cs[jtl*4+r] = c_in[(size_t)(b0+kg*4+r)*256 + nb + jtl*16];
    f32x4 acc[8];
    #pragma unroll
    for (int i=0;i<8;i++)
      acc[i] = *(const f32x4*)(gxT + ((size_t)grp*1024 + ngof(i,nb))*16 + kg*4);
    __syncthreads();

    for (int t=0; t<TSTEPS; ++t){
      if (tid==0 && t>=16 && (t&7)==0){
        unsigned need = (unsigned)(t-8);
        while (ld32(&flagC[grp]) < need) ;
      }
      __syncthreads();                       // h-writes(t-1) visible
      mfma_step(&shH[(t&1)*4096], WL, wreg, wstr, c16, kg, w, acc);
      _Float16* shn = &shH[((t+1)&1)*4096];
      unsigned long long* ring = h0r + ((size_t)(t&(H0_SLOTS-1))*16+grp)*16*128;
      unsigned long long tg = ((unsigned long long)(unsigned)(t+2))<<32;
      #pragma unroll
      for (int jtl=0;jtl<2;jtl++){
        float h4[4];
        {
          f32x4 pi=acc[jtl], pf=acc[2+jtl], pg=acc[4+jtl], po=acc[6+jtl];
          #pragma unroll
          for (int r=0;r<4;r++){
            float iv=sigx(pi[r]), fv=sigx(pf[r]), gv=tanhx(pg[r]), ov=sigx(po[r]);
            float cn = fv*cs[jtl*4+r] + iv*gv;
            cs[jtl*4+r] = cn;
            h4[r] = ov*tanhx(cn);
          }
        }
        int j = nb + jtl*16;
        #pragma unroll
        for (int r=0;r<4;r++){
          unsigned uu = (unsigned)__builtin_bit_cast(unsigned short,(_Float16)h4[r]);
          unsigned up = (unsigned)__shfl_xor((int)uu, 1, 64);
          if (!(c16 & 1)){
            unsigned pk = uu | (up<<16);
            int row = kg*4 + r;
            *(unsigned*)&shn[row*256 + ((j>>3)^(row&7))*8 + (j&7)] = pk;
            st64(&ring[(size_t)row*128 + (j>>1)], tg | pk);
          }
        }
      }
      #pragma unroll
      for (int i=0;i<8;i++)                  // re-init acc from static gx
        acc[i] = *(const f32x4*)(gxT + ((size_t)grp*1024 + ngof(i,nb))*16 + kg*4);
      #pragma unroll
      for (int kt=0;kt<8;kt++) wstr[kt] = *(const half8*)(wstrp + kt*32);
    }
  } else if (role == 1){
    // ================= partA producer =================
    float bv[8];
    #pragma unroll
    for (int i=0;i<8;i++) bv[i] = bias1[ngof(i,nb)];
    __syncthreads();
    for (int t=0; t<TSTEPS; ++t){
      if (tid==0 && t>=8 && (t&3)==0){
        unsigned need = (unsigned)(t-4);
        while (ld32(&flagB[grp]) < need) ;
      }
      { // poll h0(t) -> shH[t&1]
        int row = tid>>5, q = tid&31;
        const unsigned long long* p =
          h0r + (((size_t)(t&(H0_SLOTS-1))*16+grp)*16 + row)*128 + q*4;
        unsigned tg32 = (unsigned)(t+2);
        unsigned long long v0,v1,v2,v3;
        for (;;){
          v0=ld64(p); v1=ld64(p+1); v2=ld64(p+2); v3=ld64(p+3);
          bool ok = (unsigned)(v0>>32)==tg32 && (unsigned)(v1>>32)==tg32 &&
                    (unsigned)(v2>>32)==tg32 && (unsigned)(v3>>32)==tg32;
          if (__all(ok)) break;
        }
        G16 g; g.u[0]=(unsigned)v0; g.u[1]=(unsigned)v1;
               g.u[2]=(unsigned)v2; g.u[3]=(unsigned)v3;
        *(half8*)&shH[(t&1)*4096 + row*256 + (q^(row&7))*8] = g.h;
      }
      __syncthreads();
      if (tid==0) st32(&flagC[grp], (unsigned)(t+1));   // h0(t) consumed
      f32x4 acc[8];
      #pragma unroll
      for (int i=0;i<8;i++) acc[i] = (f32x4){bv[i],bv[i],bv[i],bv[i]};
      mfma_step(&shH[(t&1)*4096], WL, wreg, wstr, c16, kg, w, acc);
      unsigned long long tg = ((unsigned long long)(unsigned)(t+2))<<32;
      unsigned long long* rp = par + ((size_t)(t&(PA_SLOTS-1))*16+grp)*8*1024;
      #pragma unroll
      for (int i=0;i<8;i++){
        int ng = ngof(i, nb);
        #pragma unroll
        for (int q=0;q<2;q++){
          unsigned pk = pack2(acc[i][2*q], acc[i][2*q+1]);
          st64(&rp[(size_t)(kg*2+q)*1024 + ng], tg | pk);
        }
      }
      #pragma unroll
      for (int kt=0;kt<8;kt++) wstr[kt] = *(const half8*)(wstrp + kt*32);
    }
  } else {
    // ================= layer-1 recurrence =================
    { int row = tid>>5, q = tid&31;
      const float* s = h_in + 65536 + (size_t)(b0+row)*256 + q*8;
      half8 v;
      #pragma unroll
      for (int qq=0;qq<8;qq++) v[qq] = (_Float16)s[qq];
      *(half8*)&shH[row*256 + (q^(row&7))*8] = v; }            // buf 0 = h1(-1)
    float cs[8];
    #pragma unroll
    for (int jtl=0;jtl<2;jtl++)
      #pragma unroll
      for (int r=0;r<4;r++)
        cs[jtl*4+r] = c_in[65536 + (size_t)(b0+kg*4+r)*256 + nb + jtl*16];
    unsigned long long pa[8][2];
    #pragma unroll
    for (int i=0;i<8;i++)
      #pragma unroll
      for (int q=0;q<2;q++)
        pa[i][q] = ld64(&par[(((size_t)0*16+grp)*8 + kg*2+q)*1024 + ngof(i,nb)]);
    __syncthreads();

    for (int t=0; t<TSTEPS; ++t){
      unsigned tg32 = (unsigned)(t+2);
      for (;;){                              // verify prefetched partA(t)
        bool ok = true;
        #pragma unroll
        for (int i=0;i<8;i++)
          #pragma unroll
          for (int q=0;q<2;q++)
            ok = ok && ((unsigned)(pa[i][q]>>32) == tg32);
        if (__all(ok)) break;
        #pragma unroll
        for (int i=0;i<8;i++)
          #pragma unroll
          for (int q=0;q<2;q++)
            pa[i][q] = ld64(&par[(((size_t)(t&(PA_SLOTS-1))*16+grp)*8 + kg*2+q)*1024 + ngof(i,nb)]);
      }
      if (tid==0) st32(&flagB[grp], (unsigned)(t+1));   // partA(t) consumed
      f32x4 acc[8];
      #pragma unroll
      for (int i=0;i<8;i++){
        unsigned d0 = (unsigned)pa[i][0], d1 = (unsigned)pa[i][1];
        acc[i] = (f32x4){ f16lo(d0), f16hi(d0), f16lo(d1), f16hi(d1) };
      }
      __syncthreads();                       // h1-writes(t-1) visible
      mfma_step(&shH[(t&1)*4096], WL, wreg, wstr, c16, kg, w, acc);
      _Float16* shn = &shH[((t+1)&1)*4096];
      #pragma unroll
      for (int jtl=0;jtl<2;jtl++){
        float h4[4];
        {
          f32x4 pi=acc[jtl], pf=acc[2+jtl], pg=acc[4+jtl], po=acc[6+jtl];
          #pragma unroll
          for (int r=0;r<4;r++){
            float iv=sigx(pi[r]), fv=sigx(pf[r]), gv=tanhx(pg[r]), ov=sigx(po[r]);
            float cn = fv*cs[jtl*4+r] + iv*gv;
            cs[jtl*4+r] = cn;
            h4[r] = ov*tanhx(cn);
          }
        }
        int j = nb + jtl*16;
        #pragma unroll
        for (int r=0;r<4;r++){
          unsigned uu = (unsigned)__builtin_bit_cast(unsigned short,(_Float16)h4[r]);
          unsigned up = (unsigned)__shfl_xor((int)uu, 1, 64);
          if (!(c16 & 1)){
            unsigned pk = uu | (up<<16);
            int row = kg*4 + r;
            *(unsigned*)&shn[row*256 + ((j>>3)^(row&7))*8 + (j&7)] = pk;
            seq1dw[((size_t)(b0+row)*TSTEPS + t)*256 + (j>>1)] = pk;
          }
        }
      }
      if (t+1 < TSTEPS){                     // prefetch partA(t+1)
        #pragma unroll
        for (int i=0;i<8;i++)
          #pragma unroll
          for (int q=0;q<2;q++)
            pa[i][q] = ld64(&par[(((size_t)((t+1)&(PA_SLOTS-1))*16+grp)*8 + kg*2+q)*1024 + ngof(i,nb)]);
      }
      #pragma unroll
      for (int kt=0;kt<8;kt++) wstr[kt] = *(const half8*)(wstrp + kt*32);
    }
  }
}

// ---------------- FC + log_softmax / softmax ----------------
__global__ __launch_bounds__(256) void fc_kernel(
    const _Float16* __restrict__ seq, int pitch,
    const _Float16* __restrict__ fcwh, const float* __restrict__ fcb,
    float* __restrict__ out0, float* __restrict__ out1)
{
  const int tid = threadIdx.x;
  const int w = tid >> 6, l = tid & 63;
  const int col = l & 15, kg = l >> 4;
  const size_t m0 = (size_t)blockIdx.x*64 + (size_t)w*16;
  half8 a[8];
  #pragma unroll
  for (int kt=0;kt<8;kt++)
    a[kt] = *(const half8*)&seq[(m0+col)*(size_t)pitch + kt*32 + kg*8];
  f32x4 acc[16];
  #pragma unroll
  for (int nt=0;nt<16;nt++){
    int n = nt*16 + col;
    float bvl = fcb[n];
    f32x4 c = {bvl,bvl,bvl,bvl};
    const _Float16* wr = fcwh + (size_t)n*256;
    #pragma unroll
    for (int kt=0;kt<8;kt++){
      half8 bf = *(const half8*)&wr[kt*32 + kg*8];
      c = __builtin_amdgcn_mfma_f32_16x16x32_f16(a[kt], bf, c, 0,0,0);
    }
    acc[nt] = c;
  }
  #pragma unroll
  for (int r=0;r<4;r++){
    float mx = -3.0e38f;
    #pragma unroll
    for (int nt=0;nt<16;nt++) mx = fmaxf(mx, acc[nt][r]);
    #pragma unroll
    for (int off=1; off<16; off<<=1) mx = fmaxf(mx, __shfl_xor(mx, off, 64));
    float s = 0.0f;
    #pragma unroll
    for (int nt=0;nt<16;nt++) s += __expf(acc[nt][r]-mx);
    #pragma unroll
    for (int off=1; off<16; off<<=1) s += __shfl_xor(s, off, 64);
    float inv = 1.0f/s;
    float ls  = __logf(s);
    size_t row = m0 + (size_t)kg*4 + r;
    #pragma unroll
    for (int nt=0;nt<16;nt++){
      int n = nt*16 + col;
      float v = acc[nt][r]-mx;
      out0[row*256 + n] = v - ls;
      out1[row*256 + n] = __expf(v)*inv;
    }
  }
}

extern "C" void kernel_launch(void* const* d_in, const int* in_sizes, int n_in,
                              void* d_out, int out_size, void* d_ws, size_t ws_size,
                              hipStream_t stream)
{
  const float* x   = (const float*)d_in[0];
  const float* h0  = (const float*)d_in[1];
  const float* c0  = (const float*)d_in[2];
  const float* Wih = (const float*)d_in[3];
  const float* Whh = (const float*)d_in[4];
  const float* bih = (const float*)d_in[5];
  const float* bhh = (const float*)d_in[6];
  const float* fcw = (const float*)d_in[7];
  const float* fcb = (const float*)d_in[8];
  (void)in_sizes; (void)n_in; (void)out_size; (void)ws_size;

  char* ws = (char*)d_ws;
  _Float16* wh0   = (_Float16*)(ws + 0);            // 512 KB
  _Float16* wi1   = (_Float16*)(ws + (512<<10));    // 512 KB
  _Float16* wh1   = (_Float16*)(ws + (1024<<10));   // 512 KB
  _Float16* fcwh  = (_Float16*)(ws + (1536<<10));   // 128 KB
  float*    bias1 = (float*)   (ws + (1664<<10));   // 4 KB
  float*    gxT   = (float*)   (ws + (1668<<10));   // 1 MB

  // d_out scratch (out0 region, fully overwritten by fc at the end):
  //   h0ring 4MB | paring 8MB | flagC 64B | flagB 64B
  char* ob = (char*)d_out;
  float* out0 = (float*)d_out;
  float* out1 = out0 + (size_t)BATCH*TSTEPS*OUTC;
  unsigned long long* h0r   = (unsigned long long*)ob;
  unsigned long long* par   = h0r + H0RING_QW;
  unsigned*           flagC = (unsigned*)(par + PARING_QW);
  unsigned*           flagB = flagC + 16;
  unsigned* seq1dw = (unsigned*)out1;               // seq1 overlay, pitch 512 f16
  _Float16* seq1   = (_Float16*)out1;

  const int zeroQW = H0RING_QW + PARING_QW + 16;
  hipLaunchKernelGGL(zero_scratch, dim3((zeroQW+255)/256), dim3(256), 0, stream,
                     h0r, zeroQW);
  hipLaunchKernelGGL(prep_convert, dim3(1024), dim3(256), 0, stream,
                     Wih, Whh, fcw, bih, bhh, wh0, wi1, wh1, fcwh, bias1);
  hipLaunchKernelGGL(prep_gx0, dim3(1024), dim3(256), 0, stream,
                     x, Wih, bih, bhh, gxT);
  hipLaunchKernelGGL(lstm3, dim3(48), dim3(512), 0, stream,
                     gxT, wh0, wi1, wh1, bias1, h0, c0,
                     seq1dw, h0r, par, flagC, flagB);
  hipLaunchKernelGGL(fc_kernel, dim3(2048), dim3(256), 0, stream,
                     seq1, 512, fcwh, fcb, out0, out1);
}

// Round 6
// 1810.113 us; speedup vs baseline: 3.6874x; 3.6874x over previous
//
#include <hip/hip_runtime.h>

#define TSTEPS 512
#define BATCH  256
#define HID    256
#define OUTC   256

typedef _Float16 half8 __attribute__((ext_vector_type(8)));
typedef float    f32x4 __attribute__((ext_vector_type(4)));
union G16 { unsigned long long u2[2]; unsigned u[4]; half8 h; };

// rings in d_out scratch: entry = u64 (lo: 2xf16 data, hi: tag = step+2; 0 invalid)
// h0 ring: [16 slots][16 grp][16 row][128 pair]  (4 MB)
// h1 ring: [ 4 slots][16 grp][16 row][128 pair]  (1 MB)
#define H0_SLOTS 16
#define H1_SLOTS 4
#define H0RING_QW (H0_SLOTS*16*16*128)
#define H1RING_QW (H1_SLOTS*16*16*128)

__device__ __forceinline__ float sigf(float x){ return 1.0f/(1.0f+__expf(-x)); }
__device__ __forceinline__ float tanh_(float x){
  float a = fminf(fmaxf(x,-8.0f),8.0f);
  float e = __expf(2.0f*a);
  return (e-1.0f)/(e+1.0f);
}
__device__ __forceinline__ void st64(unsigned long long* p, unsigned long long v){
  __hip_atomic_store(p, v, __ATOMIC_RELAXED, __HIP_MEMORY_SCOPE_AGENT);
}
__device__ __forceinline__ unsigned long long ld64(const unsigned long long* p){
  return __hip_atomic_load(p, __ATOMIC_RELAXED, __HIP_MEMORY_SCOPE_AGENT);
}
__device__ __forceinline__ void st32(unsigned* p, unsigned v){
  __hip_atomic_store(p, v, __ATOMIC_RELAXED, __HIP_MEMORY_SCOPE_AGENT);
}
__device__ __forceinline__ unsigned ld32(const unsigned* p){
  return __hip_atomic_load(p, __ATOMIC_RELAXED, __HIP_MEMORY_SCOPE_AGENT);
}
__device__ __forceinline__ unsigned pack2(float a, float b){
  _Float16 x=(_Float16)a, y=(_Float16)b;
  return (unsigned)__builtin_bit_cast(unsigned short,x)
       | ((unsigned)__builtin_bit_cast(unsigned short,y)<<16);
}

// ---------------- prep kernels ----------------
__global__ void prep_convert(const float* __restrict__ Wih, const float* __restrict__ Whh,
                             const float* __restrict__ fcw, const float* __restrict__ bih,
                             const float* __restrict__ bhh,
                             _Float16* __restrict__ wh0, _Float16* __restrict__ wi1,
                             _Float16* __restrict__ wh1, _Float16* __restrict__ fcwh,
                             float* __restrict__ bias1)
{
  int i = blockIdx.x*256 + threadIdx.x;
  wh0[i] = (_Float16)Whh[i];
  wi1[i] = (_Float16)Wih[262144 + i];
  wh1[i] = (_Float16)Whh[262144 + i];
  if (i < 65536) fcwh[i] = (_Float16)fcw[i];
  if (i < 1024)  bias1[i] = bih[1024+i] + bhh[1024+i];
}

__global__ void prep_gx0(const float* __restrict__ x, const float* __restrict__ Wih,
                         const float* __restrict__ bih, const float* __restrict__ bhh,
                         float* __restrict__ gx0)
{
  int gid = blockIdx.x*256 + threadIdx.x;
  int b = gid >> 10, n = gid & 1023;
  const float4* xv = (const float4*)(x + (size_t)b*256);
  const float4* wv = (const float4*)(Wih + (size_t)n*256);
  float s = bih[n] + bhh[n];
  #pragma unroll 8
  for (int k=0;k<64;k++){
    float4 a = xv[k], c = wv[k];
    s += a.x*c.x + a.y*c.y + a.z*c.z + a.w*c.w;
  }
  gx0[gid] = s;
}

__global__ void zero_scratch(unsigned long long* __restrict__ base, int total){
  int i = blockIdx.x*256 + threadIdx.x;
  if (i < total) st64(base + i, 0ull);
}

// ================= fused 2-layer LSTM: 192 WGs =================
// blk<64:  layer0. 16 grps x 4 j-slices (64 cols). Wh0 slice 128 KB in LDS.
//          Recurrence LDS-local; ring publish fire-and-forget; poll 3 peers.
// blk>=64: layer1. 16 grps x 8 j-slices (32 cols). [Wi1|Wh1] slice 128 KB LDS.
//          h0 reg-prefetched 1 step ahead; own h1 cols LDS-local; gather 7 peers.
__global__ __launch_bounds__(512,1) void lstm4(
    const float* __restrict__ gx0, const _Float16* __restrict__ Wh0g,
    const _Float16* __restrict__ Wi1g, const _Float16* __restrict__ Wh1g,
    const float* __restrict__ bias1, const float* __restrict__ h_in,
    const float* __restrict__ c_in, unsigned* __restrict__ seq1dw,
    unsigned long long* __restrict__ h0r, unsigned long long* __restrict__ h1r,
    unsigned* __restrict__ flagC)
{
  __shared__ __align__(16) char Lb[156160];
  _Float16* Ws  = (_Float16*)Lb;              // 128 KB weights
  _Float16* sh0 = (_Float16*)(Lb + 131072);   // 8 KB h0 tile (swizzled)

  const int blk = blockIdx.x, tid = threadIdx.x;
  const int wv = tid>>6, l = tid&63, c16 = l&15, kg = l>>4;

  if (blk < 64){
    // ---------------- layer 0 ----------------
    const int grp = blk>>2, s = blk&3, b0 = grp*16;
    const int gate = wv>>1, jblk = (wv&1)*32;
    float (*gbuf)[16][66] = (float (*)[16][66])(Lb + 139264);  // 16.9 KB

    for (int idx=tid; idx<8192; idx+=512){
      int row = idx>>5, gr = idx&31;
      int g = row>>6, jl = row&63;
      half8 v = *(const half8*)(Wh0g + ((size_t)(g*256 + s*64 + jl))*256 + gr*8);
      *(half8*)&Ws[row*256 + (gr^(row&7))*8] = v;
    }
    { int row = tid>>5, q = tid&31;
      const float* sp = h_in + (size_t)(b0+row)*256 + q*8;
      half8 v;
      #pragma unroll
      for (int qq=0;qq<8;qq++) v[qq] = (_Float16)sp[qq];
      *(half8*)&sh0[row*256 + (q^(row&7))*8] = v; }
    const int eb = tid>>5, jp = tid&31;
    float cA = c_in[(size_t)(b0+eb)*256 + s*64 + 2*jp];
    float cB = c_in[(size_t)(b0+eb)*256 + s*64 + 2*jp + 1];
    float gxr[2][4];
    #pragma unroll
    for (int nt=0;nt<2;nt++)
      #pragma unroll
      for (int r=0;r<4;r++)
        gxr[nt][r] = gx0[(size_t)(b0 + kg*4 + r)*1024 + gate*256 + s*64 + jblk + nt*16 + c16];
    const int r0 = gate*64 + jblk + c16, r1 = r0 + 16;
    __syncthreads();

    for (int t=0; t<TSTEPS; ++t){
      // throttle vs l1 consumption (every 8 steps, 8-step slack, wave0 only)
      if (((t&7)==0) && t>=16 && tid<64){
        const unsigned need = (unsigned)(t-8);
        bool ok;
        do {
          unsigned v = need;
          if (tid < 8) v = ld32(&flagC[grp*8 + tid]);
          ok = (v >= need);
        } while (!__all(ok));
      }
      f32x4 acc0 = { gxr[0][0], gxr[0][1], gxr[0][2], gxr[0][3] };
      f32x4 acc1 = { gxr[1][0], gxr[1][1], gxr[1][2], gxr[1][3] };
      #pragma unroll
      for (int kt=0;kt<8;kt++){
        half8 af  = *(const half8*)&sh0[c16*256 + ((kt*4+kg)^(c16&7))*8];
        half8 b0f = *(const half8*)&Ws[r0*256 + ((kt*4+kg)^(r0&7))*8];
        half8 b1f = *(const half8*)&Ws[r1*256 + ((kt*4+kg)^(r1&7))*8];
        acc0 = __builtin_amdgcn_mfma_f32_16x16x32_f16(af, b0f, acc0, 0,0,0);
        acc1 = __builtin_amdgcn_mfma_f32_16x16x32_f16(af, b1f, acc1, 0,0,0);
      }
      #pragma unroll
      for (int r=0;r<4;r++){
        gbuf[gate][kg*4+r][jblk + c16]      = acc0[r];
        gbuf[gate][kg*4+r][jblk + 16 + c16] = acc1[r];
      }
      __syncthreads();      // gbuf ready AND all sh0 MFMA reads done
      { // cell: own 2 cols -> sh0 (LDS-local recurrence) + ring publish
        int j0 = 2*jp, j1 = 2*jp+1;
        float i0 = sigf (gbuf[0][eb][j0]), i1 = sigf (gbuf[0][eb][j1]);
        float f0 = sigf (gbuf[1][eb][j0]), f1 = sigf (gbuf[1][eb][j1]);
        float g0 = tanh_(gbuf[2][eb][j0]), g1 = tanh_(gbuf[2][eb][j1]);
        float o0 = sigf (gbuf[3][eb][j0]), o1 = sigf (gbuf[3][eb][j1]);
        cA = f0*cA + i0*g0;
        cB = f1*cB + i1*g1;
        unsigned pk = pack2(o0*tanh_(cA), o1*tanh_(cB));
        int jg = s*64 + j0;
        *(unsigned*)&sh0[eb*256 + ((jg>>3)^(eb&7))*8 + (jg&7)] = pk;
        st64(&h0r[(((size_t)(t&(H0_SLOTS-1))*16+grp)*16 + eb)*128 + s*32 + jp],
             (((unsigned long long)(unsigned)(t+2))<<32) | pk);
      }
      { // poll 3 peer segments of h0(t)
        int row = tid>>5, q = tid&31;
        if ((q>>3) != s){
          const unsigned long long* p =
            h0r + (((size_t)(t&(H0_SLOTS-1))*16+grp)*16 + row)*128 + q*4;
          unsigned tg32 = (unsigned)(t+2);
          unsigned long long v0,v1,v2,v3;
          for(;;){
            v0=ld64(p); v1=ld64(p+1); v2=ld64(p+2); v3=ld64(p+3);
            bool ok = (unsigned)(v0>>32)==tg32 && (unsigned)(v1>>32)==tg32 &&
                      (unsigned)(v2>>32)==tg32 && (unsigned)(v3>>32)==tg32;
            if (__all(ok)) break;
          }
          G16 g; g.u[0]=(unsigned)v0; g.u[1]=(unsigned)v1;
                 g.u[2]=(unsigned)v2; g.u[3]=(unsigned)v3;
          *(half8*)&sh0[row*256 + (q^(row&7))*8] = g.h;
        }
      }
      __syncthreads();      // sh0 = h0(t) complete
    }
  } else {
    // ---------------- layer 1 ----------------
    const int bb = blk-64, grp = bb>>3, js = bb&7;
    const int b0 = grp*16, jb = js*32;
    const int gate = wv>>1, jhalf = (wv&1)*16;
    _Float16* sh1 = (_Float16*)(Lb + 139264);                  // 8 KB
    float (*gbuf)[16][34] = (float (*)[16][34])(Lb + 147456);  // 8.7 KB

    for (int idx=tid; idx<8192; idx+=512){
      int row = idx>>6, gr = idx&63;
      int g = row>>5, jl = row&31;
      size_t nrow = (size_t)(g*256 + jb + jl);
      const _Float16* src = (gr < 32) ? (Wi1g + nrow*256 + gr*8)
                                      : (Wh1g + nrow*256 + (size_t)(gr-32)*8);
      *(half8*)&Ws[row*512 + (gr^(row&7))*8] = *(const half8*)src;
    }
    { int row = tid>>5, q = tid&31;
      const float* sp = h_in + 65536 + (size_t)(b0+row)*256 + q*8;
      half8 v;
      #pragma unroll
      for (int qq=0;qq<8;qq++) v[qq] = (_Float16)sp[qq];
      *(half8*)&sh1[row*256 + (q^(row&7))*8] = v; }
    const int eb = tid>>4, jp = tid&15;     // cell mapping (tid<256)
    float cA = 0.f, cB = 0.f;
    if (tid < 256){
      cA = c_in[65536 + (size_t)(b0+eb)*256 + jb + 2*jp];
      cB = c_in[65536 + (size_t)(b0+eb)*256 + jb + 2*jp + 1];
    }
    const float bv = bias1[gate*256 + jb + jhalf + c16];
    const int nl = gate*32 + jhalf + c16;
    const int prow = tid>>5, pq = tid&31;   // poll mapping
    // prefetch h0(0): slot 0, tag 2
    unsigned long long hv0,hv1,hv2,hv3;
    {
      const unsigned long long* p = h0r + (((size_t)grp)*16 + prow)*128 + pq*4;
      hv0=ld64(p); hv1=ld64(p+1); hv2=ld64(p+2); hv3=ld64(p+3);
    }
    __syncthreads();

    for (int t=0; t<TSTEPS; ++t){
      { // verify prefetched h0(t); reload on miss; stage to sh0
        unsigned tg32 = (unsigned)(t+2);
        const unsigned long long* p =
          h0r + (((size_t)(t&(H0_SLOTS-1))*16+grp)*16 + prow)*128 + pq*4;
        for(;;){
          bool ok = (unsigned)(hv0>>32)==tg32 && (unsigned)(hv1>>32)==tg32 &&
                    (unsigned)(hv2>>32)==tg32 && (unsigned)(hv3>>32)==tg32;
          if (__all(ok)) break;
          hv0=ld64(p); hv1=ld64(p+1); hv2=ld64(p+2); hv3=ld64(p+3);
        }
        G16 g; g.u[0]=(unsigned)hv0; g.u[1]=(unsigned)hv1;
               g.u[2]=(unsigned)hv2; g.u[3]=(unsigned)hv3;
        *(half8*)&sh0[prow*256 + (pq^(prow&7))*8] = g.h;
      }
      __syncthreads();      // sh0 = h0(t) ready; prior-step sh0 reads done
      if (((t&7)==0) && tid==0) st32(&flagC[grp*8+js], (unsigned)t);
      // partA: bias + Wi1 . h0(t)
      f32x4 acc = { bv, bv, bv, bv };
      #pragma unroll
      for (int kt=0;kt<8;kt++){
        half8 af = *(const half8*)&sh0[c16*256 + ((kt*4+kg)^(c16&7))*8];
        half8 bf = *(const half8*)&Ws[nl*512 + ((kt*4+kg)^(nl&7))*8];
        acc = __builtin_amdgcn_mfma_f32_16x16x32_f16(af, bf, acc, 0,0,0);
      }
      // gather h1(t-1) from 7 peers (own cols already LDS-local)
      if (t > 0 && (pq>>2) != js){
        const unsigned long long* p =
          h1r + (((size_t)((t+3)&(H1_SLOTS-1))*16+grp)*16 + prow)*128 + pq*4;
        unsigned tg32 = (unsigned)(t+1);
        unsigned long long v0,v1,v2,v3;
        for(;;){
          v0=ld64(p); v1=ld64(p+1); v2=ld64(p+2); v3=ld64(p+3);
          bool ok = (unsigned)(v0>>32)==tg32 && (unsigned)(v1>>32)==tg32 &&
                    (unsigned)(v2>>32)==tg32 && (unsigned)(v3>>32)==tg32;
          if (__all(ok)) break;
        }
        G16 g; g.u[0]=(unsigned)v0; g.u[1]=(unsigned)v1;
               g.u[2]=(unsigned)v2; g.u[3]=(unsigned)v3;
        *(half8*)&sh1[prow*256 + (pq^(prow&7))*8] = g.h;
      }
      __syncthreads();      // sh1 = h1(t-1) complete
      // partB: += Wh1 . h1(t-1)
      #pragma unroll
      for (int kt=0;kt<8;kt++){
        half8 af = *(const half8*)&sh1[c16*256 + ((kt*4+kg)^(c16&7))*8];
        half8 bf = *(const half8*)&Ws[nl*512 + ((32+kt*4+kg)^(nl&7))*8];
        acc = __builtin_amdgcn_mfma_f32_16x16x32_f16(af, bf, acc, 0,0,0);
      }
      #pragma unroll
      for (int r=0;r<4;r++) gbuf[gate][kg*4+r][jhalf + c16] = acc[r];
      __syncthreads();      // gbuf ready AND sh1 reads done
      if (tid < 256){       // cell + publish + seq1
        int j0 = 2*jp, j1 = 2*jp+1;
        float i0 = sigf (gbuf[0][eb][j0]), i1 = sigf (gbuf[0][eb][j1]);
        float f0 = sigf (gbuf[1][eb][j0]), f1 = sigf (gbuf[1][eb][j1]);
        float g0 = tanh_(gbuf[2][eb][j0]), g1 = tanh_(gbuf[2][eb][j1]);
        float o0 = sigf (gbuf[3][eb][j0]), o1 = sigf (gbuf[3][eb][j1]);
        cA = f0*cA + i0*g0;
        cB = f1*cB + i1*g1;
        unsigned pk = pack2(o0*tanh_(cA), o1*tanh_(cB));
        int jg = jb + j0;
        *(unsigned*)&sh1[eb*256 + ((jg>>3)^(eb&7))*8 + (jg&7)] = pk;
        st64(&h1r[(((size_t)(t&(H1_SLOTS-1))*16+grp)*16 + eb)*128 + js*16 + jp],
             (((unsigned long long)(unsigned)(t+2))<<32) | pk);
        seq1dw[((size_t)(b0+eb)*TSTEPS + t)*256 + js*16 + jp] = pk;
      }
      if (t+1 < TSTEPS){    // prefetch h0(t+1), verified at next step start
        const unsigned long long* p =
          h0r + (((size_t)((t+1)&(H0_SLOTS-1))*16+grp)*16 + prow)*128 + pq*4;
        hv0=ld64(p); hv1=ld64(p+1); hv2=ld64(p+2); hv3=ld64(p+3);
      }
    }
  }
}

// ---------------- FC + log_softmax / softmax ----------------
__global__ __launch_bounds__(256) void fc_kernel(
    const _Float16* __restrict__ seq, int pitch,
    const _Float16* __restrict__ fcwh, const float* __restrict__ fcb,
    float* __restrict__ out0, float* __restrict__ out1)
{
  const int tid = threadIdx.x;
  const int w = tid >> 6, l = tid & 63;
  const int col = l & 15, kg = l >> 4;
  const size_t m0 = (size_t)blockIdx.x*64 + (size_t)w*16;
  half8 a[8];
  #pragma unroll
  for (int kt=0;kt<8;kt++)
    a[kt] = *(const half8*)&seq[(m0+col)*(size_t)pitch + kt*32 + kg*8];
  f32x4 acc[16];
  #pragma unroll
  for (int nt=0;nt<16;nt++){
    int n = nt*16 + col;
    float bvl = fcb[n];
    f32x4 c = {bvl,bvl,bvl,bvl};
    const _Float16* wr = fcwh + (size_t)n*256;
    #pragma unroll
    for (int kt=0;kt<8;kt++){
      half8 bf = *(const half8*)&wr[kt*32 + kg*8];
      c = __builtin_amdgcn_mfma_f32_16x16x32_f16(a[kt], bf, c, 0,0,0);
    }
    acc[nt] = c;
  }
  #pragma unroll
  for (int r=0;r<4;r++){
    float mx = -3.0e38f;
    #pragma unroll
    for (int nt=0;nt<16;nt++) mx = fmaxf(mx, acc[nt][r]);
    #pragma unroll
    for (int off=1; off<16; off<<=1) mx = fmaxf(mx, __shfl_xor(mx, off, 64));
    float s = 0.0f;
    #pragma unroll
    for (int nt=0;nt<16;nt++) s += __expf(acc[nt][r]-mx);
    #pragma unroll
    for (int off=1; off<16; off<<=1) s += __shfl_xor(s, off, 64);
    float inv = 1.0f/s;
    float ls  = __logf(s);
    size_t row = m0 + (size_t)kg*4 + r;
    #pragma unroll
    for (int nt=0;nt<16;nt++){
      int n = nt*16 + col;
      float v = acc[nt][r]-mx;
      out0[row*256 + n] = v - ls;
      out1[row*256 + n] = __expf(v)*inv;
    }
  }
}

extern "C" void kernel_launch(void* const* d_in, const int* in_sizes, int n_in,
                              void* d_out, int out_size, void* d_ws, size_t ws_size,
                              hipStream_t stream)
{
  const float* x   = (const float*)d_in[0];
  const float* h0  = (const float*)d_in[1];
  const float* c0  = (const float*)d_in[2];
  const float* Wih = (const float*)d_in[3];
  const float* Whh = (const float*)d_in[4];
  const float* bih = (const float*)d_in[5];
  const float* bhh = (const float*)d_in[6];
  const float* fcw = (const float*)d_in[7];
  const float* fcb = (const float*)d_in[8];
  (void)in_sizes; (void)n_in; (void)out_size; (void)ws_size;

  char* ws = (char*)d_ws;
  _Float16* wh0   = (_Float16*)(ws + 0);            // 512 KB
  _Float16* wi1   = (_Float16*)(ws + (512<<10));    // 512 KB
  _Float16* wh1   = (_Float16*)(ws + (1024<<10));   // 512 KB
  _Float16* fcwh  = (_Float16*)(ws + (1536<<10));   // 128 KB
  float*    bias1 = (float*)   (ws + (1664<<10));   // 4 KB
  float*    gx0   = (float*)   (ws + (1668<<10));   // 1 MB

  // d_out scratch (out0 region, fully overwritten by fc at the end):
  //   h0 ring 4 MB | h1 ring 1 MB | flagC 512 B
  char* ob = (char*)d_out;
  float* out0 = (float*)d_out;
  float* out1 = out0 + (size_t)BATCH*TSTEPS*OUTC;
  unsigned long long* h0r   = (unsigned long long*)ob;
  unsigned long long* h1r   = h0r + H0RING_QW;
  unsigned*           flagC = (unsigned*)(h1r + H1RING_QW);
  unsigned* seq1dw = (unsigned*)out1;               // seq1 overlay, pitch 512 f16
  _Float16* seq1   = (_Float16*)out1;

  const int zeroQW = H0RING_QW + H1RING_QW + 64;
  hipLaunchKernelGGL(zero_scratch, dim3((zeroQW+255)/256), dim3(256), 0, stream,
                     h0r, zeroQW);
  hipLaunchKernelGGL(prep_convert, dim3(1024), dim3(256), 0, stream,
                     Wih, Whh, fcw, bih, bhh, wh0, wi1, wh1, fcwh, bias1);
  hipLaunchKernelGGL(prep_gx0, dim3(1024), dim3(256), 0, stream,
                     x, Wih, bih, bhh, gx0);
  hipLaunchKernelGGL(lstm4, dim3(192), dim3(512), 0, stream,
                     gx0, wh0, wi1, wh1, bias1, h0, c0,
                     seq1dw, h0r, h1r, flagC);
  hipLaunchKernelGGL(fc_kernel, dim3(2048), dim3(256), 0, stream,
                     seq1, 512, fcwh, fcb, out0, out1);
}